// Round 1
// baseline (246.180 us; speedup 1.0000x reference)
//
#include <hip/hip_runtime.h>
#include <hip/hip_bf16.h>
#include <math.h>

typedef __hip_bfloat16 bf16t;
typedef __attribute__((ext_vector_type(8))) short short8;
typedef __attribute__((ext_vector_type(4))) float f32x4;

#define DI 1024
#define NSTATE 16
#define TLEN 2048
#define LOG2E 1.4426950408889634f

__device__ __forceinline__ float b2f(bf16t v) { return __bfloat162float(v); }
__device__ __forceinline__ bf16t f2b(float v) { return __float2bfloat16(v); }
__device__ __forceinline__ float fexp2(float x) { return __builtin_amdgcn_exp2f(x); }
__device__ __forceinline__ float flog2(float x) { return __builtin_amdgcn_logf(x); }
__device__ __forceinline__ float softplus_fast(float v) {
  return (v > 20.f) ? v : flog2(1.f + fexp2(v * LOG2E)) * (1.f / LOG2E);
}
__device__ __forceinline__ short bs(float v) { bf16t h = f2b(v); return *(short*)&h; }
__device__ __forceinline__ float sb(short v) { return b2f(*(bf16t*)&v); }

// wave-ballot dtype detect on first 64 words of x: 1 = fp32 inputs, 0 = bf16
__device__ __forceinline__ int detect_f(const unsigned int* __restrict__ x0) {
  unsigned int w = x0[threadIdx.x & 63];
  int e = (w >> 7) & 0xFF;
  unsigned long long m = __ballot(e >= 110 && e <= 135);
  return (__popcll(m) < 32) ? 1 : 0;
}

// runtime-dtype load for RAW INPUTS: f=1 -> fp32, f=0 -> bf16
__device__ __forceinline__ float load_any(const void* s, long i, int f) {
  return f ? ((const float*)s)[i] : b2f(((const bf16t*)s)[i]);
}

__device__ __forceinline__ void async16(const void* g, void* l) {
  __builtin_amdgcn_global_load_lds(
      (const __attribute__((address_space(1))) unsigned int*)g,
      (__attribute__((address_space(3))) unsigned int*)l, 16, 0, 0);
}

template <int N> __device__ __forceinline__ void waitcnt_vm() {
  if constexpr (N == 0)      asm volatile("s_waitcnt vmcnt(0)" ::: "memory");
  else if constexpr (N == 2) asm volatile("s_waitcnt vmcnt(2)" ::: "memory");
  else if constexpr (N == 3) asm volatile("s_waitcnt vmcnt(3)" ::: "memory");
  else if constexpr (N == 4) asm volatile("s_waitcnt vmcnt(4)" ::: "memory");
  else if constexpr (N == 6) asm volatile("s_waitcnt vmcnt(6)" ::: "memory");
  else if constexpr (N == 8) asm volatile("s_waitcnt vmcnt(8)" ::: "memory");
}
__device__ __forceinline__ void raw_barrier() { asm volatile("s_barrier" ::: "memory"); }

// ---------------- bf16 cast of all 5 GEMM matrices (hi planes only)
// big (aliased over P/S): x[0,2097152) w1[2097152,3145728)
// small (persistent): xw[0,65536) w3[65536,589824) dtw[589824,622592)
__global__ __launch_bounds__(256) void cast_h(
    const void* __restrict__ x, const void* __restrict__ w1,
    const void* __restrict__ xw, const void* __restrict__ w3, const void* __restrict__ dtw,
    short* __restrict__ bigH, short* __restrict__ smallH)
{
  int f = detect_f((const unsigned int*)x);
  int i0 = (blockIdx.x * 256 + threadIdx.x) * 4;
#pragma unroll
  for (int q = 0; q < 4; q++) {
    int i = i0 + q;
    if (i >= 3768320) return;
    if (i < 3145728) {
      float v = (i < 2097152) ? load_any(x, i, f) : load_any(w1, i - 2097152, f);
      bigH[i] = bs(v);
    } else {
      int j = i - 3145728;
      float v;
      if (j < 65536)       v = load_any(xw, j, f);
      else if (j < 589824) v = load_any(w3, j - 65536, f);
      else                 v = load_any(dtw, j - 589824, f);
      smallH[j] = bs(v);
    }
  }
}

// ---------------- bf16 MFMA GEMM, 3-deep LDS ring (2-tile-ahead prefetch, counted vmcnt)
// C[M,N] = A[M,K] * B[N,K]^T
// MODE 0: fp32 C. MODE 1: +bias softplus -> bf16 outH. MODE 2: fp32 C + bf16 cols<32.
// MODE 3 (in_proj): cols<1024 -> bf16 outH (raw); cols>=1024 -> silu -> bf16 out2.
template <int BM, int BN, int MODE>
__global__ __launch_bounds__(256) void gemm_mf(
    const short* __restrict__ Ah, const short* __restrict__ Bh,
    float* __restrict__ C, int K, int lda, int ldb, int ldc,
    const void* __restrict__ bias, const unsigned int* __restrict__ x0,
    short* __restrict__ outH, short* __restrict__ out2)
{
  constexpr int NFM = BM / 32, NFN = BN / 32;
  constexpr int SA = BM / 64, SB = BN / 64;
  constexpr int NL = SA + SB;
  __shared__ __align__(16) short lA[3 * BM * 32];
  __shared__ __align__(16) short lB[3 * BN * 32];
  int tid = threadIdx.x;
  int lane = tid & 63, wave = tid >> 6;
  int bm = blockIdx.x * BM, bn = blockIdx.y * BN;
  int wm = (wave & 1) * (BM / 2), wn = (wave >> 1) * (BN / 2);
  f32x4 acc[NFM][NFN] = {};
  int r0 = tid >> 2, kp = (tid & 3) * 8;
  const short* pA = Ah + (size_t)(bm + r0) * lda + kp;
  const short* pB = Bh + (size_t)(bn + r0) * ldb + kp;
  int ldsOff = tid * 8;
  int la = (lane & 15) * 32 + (lane >> 4) * 8;
  int nIter = K / 32;

  auto stage = [&](int kk, int b) {
    int off = kk * 32;
#pragma unroll
    for (int s = 0; s < SA; s++)
      async16(pA + off + (size_t)s * 64 * lda, &lA[b * BM * 32 + ldsOff + s * 64 * 32]);
#pragma unroll
    for (int s = 0; s < SB; s++)
      async16(pB + off + (size_t)s * 64 * ldb, &lB[b * BN * 32 + ldsOff + s * 64 * 32]);
  };

  stage(0, 0);
  if (nIter > 1) stage(1, 1);
  int cur = 0;
  for (int kk = 0; kk < nIter; kk++) {
    if (kk + 2 < nIter) {
      int s = cur + 2; if (s >= 3) s -= 3;
      stage(kk + 2, s);
      waitcnt_vm<2 * NL>();
    } else if (kk + 1 < nIter) {
      waitcnt_vm<NL>();
    } else {
      waitcnt_vm<0>();
    }
    raw_barrier();
    short8 af[NFM], bf[NFN];
#pragma unroll
    for (int i = 0; i < NFM; i++)
      af[i] = *(const short8*)&lA[cur * BM * 32 + (wm + i * 16) * 32 + la];
#pragma unroll
    for (int j = 0; j < NFN; j++)
      bf[j] = *(const short8*)&lB[cur * BN * 32 + (wn + j * 16) * 32 + la];
#pragma unroll
    for (int i = 0; i < NFM; i++)
#pragma unroll
      for (int j = 0; j < NFN; j++)
        acc[i][j] = __builtin_amdgcn_mfma_f32_16x16x32_bf16(af[i], bf[j], acc[i][j], 0, 0, 0);
    raw_barrier();
    cur++; if (cur == 3) cur = 0;
  }
  int f = (MODE == 1) ? detect_f(x0) : 0;
  int rbase = (lane >> 4) * 4, ncol = lane & 15;
#pragma unroll
  for (int i = 0; i < NFM; i++)
#pragma unroll
    for (int j = 0; j < NFN; j++)
#pragma unroll
      for (int r = 0; r < 4; r++) {
        int m = bm + wm + i * 16 + rbase + r;
        int n = bn + wn + j * 16 + ncol;
        float v = acc[i][j][r];
        if constexpr (MODE == 1) {
          v = softplus_fast(v + load_any(bias, n, f));
          outH[(size_t)m * ldc + n] = bs(v);
        } else if constexpr (MODE == 3) {
          if (n < 1024) {
            outH[(size_t)m * 1024 + n] = bs(v);                       // raw x half
          } else {
            float gv = v / (1.f + fexp2(-v * LOG2E));                 // silu(gate)
            out2[(size_t)m * 1024 + (n - 1024)] = bs(gv);
          }
        } else {
          C[(size_t)m * ldc + n] = v;
          if constexpr (MODE == 2) {
            if (n < 32) outH[(size_t)m * 32 + n] = bs(v);
          }
        }
      }
}

// ---------------- fused x_proj + dt_proj
// Phase 1: per block, rows [bm,bm+64): S_tile[64,64] = xt @ xw^T (K=1024, 4-deep ring).
//   blockIdx.y in [0,4) replicate phase 1 (cheap) so the chip is full.
//   y==0 waves with wn==32 write ssm fp32 cols 32..64; waves wn==0 park cols 0..32 in LDS (bf16).
// Phase 2: dt = softplus(S_tile[:,0:32] @ dtw^T + dtb) for col-block y (256 cols), K=32 MFMA
//   from LDS; dtw tile pre-staged via global_load_lds at entry (hides under phase 1).
__global__ __launch_bounds__(256) void xdt_gemm(
    const short* __restrict__ Ah,   // xt_h [4096,1024] bf16
    const short* __restrict__ Bh,   // xw   [64,1024]  bf16
    const short* __restrict__ Wdt,  // dtw  [1024,32]  bf16
    float* __restrict__ ssm,        // [4096,64] fp32 (cols 32..64 written)
    const void* __restrict__ dtb, const unsigned int* __restrict__ x0,
    short* __restrict__ dtf)        // [4096,1024] bf16
{
  __shared__ __align__(16) short lA[4 * 64 * 32];
  __shared__ __align__(16) short lB[4 * 64 * 32];
  __shared__ __align__(16) short lW[256 * 32];
  __shared__ __align__(16) short lS[64 * 32];
  int tid = threadIdx.x;
  int lane = tid & 63, wave = tid >> 6;
  int bm = blockIdx.x * 64;
  int cby = blockIdx.y;
  int wm = (wave & 1) * 32, wn = (wave >> 1) * 32;
  f32x4 acc[2][2] = {};
  int r0 = tid >> 2, kp = (tid & 3) * 8;
  const short* pA = Ah + (size_t)(bm + r0) * 1024 + kp;
  const short* pB = Bh + (size_t)r0 * 1024 + kp;
  int ldsOff = tid * 8;
  int la = (lane & 15) * 32 + (lane >> 4) * 8;

  auto stg = [&](int kk, int b) {
    async16(pA + kk * 32, &lA[b * 2048 + ldsOff]);
    async16(pB + kk * 32, &lB[b * 2048 + ldsOff]);
  };
  // prologue: 3 K-tiles ahead, then the phase-2 dtw tile (newest in vmcnt queue)
  stg(0, 0); stg(1, 1); stg(2, 2);
#pragma unroll
  for (int q = 0; q < 4; q++)
    async16(Wdt + (size_t)cby * 8192 + (q * 256 + tid) * 8, &lW[(q * 256 + tid) * 8]);

  for (int kk = 0; kk < 32; kk++) {
    int cur = kk & 3;
    if (kk + 3 < 32) {
      stg(kk + 3, (kk + 3) & 3);
      waitcnt_vm<6>();
    } else if (kk + 2 < 32) waitcnt_vm<4>();
    else if (kk + 1 < 32)   waitcnt_vm<2>();
    else                    waitcnt_vm<0>();
    raw_barrier();
    short8 af[2], bf2[2];
#pragma unroll
    for (int i = 0; i < 2; i++)
      af[i] = *(const short8*)&lA[cur * 2048 + (wm + i * 16) * 32 + la];
#pragma unroll
    for (int j = 0; j < 2; j++)
      bf2[j] = *(const short8*)&lB[cur * 2048 + (wn + j * 16) * 32 + la];
#pragma unroll
    for (int i = 0; i < 2; i++)
#pragma unroll
      for (int j = 0; j < 2; j++)
        acc[i][j] = __builtin_amdgcn_mfma_f32_16x16x32_bf16(af[i], bf2[j], acc[i][j], 0, 0, 0);
    raw_barrier();
  }
  int rbase = (lane >> 4) * 4, ncol = lane & 15;
  if (wn == 0) {
    // dt-input slice (cols 0..32) -> lS bf16 (same rounding point as old sdH)
#pragma unroll
    for (int i = 0; i < 2; i++)
#pragma unroll
      for (int j = 0; j < 2; j++)
#pragma unroll
        for (int r = 0; r < 4; r++)
          lS[(wm + i * 16 + rbase + r) * 32 + j * 16 + ncol] = bs(acc[i][j][r]);
  } else if (cby == 0) {
    // B,C cols (32..64) -> ssm fp32, written once (y==0)
#pragma unroll
    for (int i = 0; i < 2; i++)
#pragma unroll
      for (int j = 0; j < 2; j++)
#pragma unroll
        for (int r = 0; r < 4; r++)
          ssm[(size_t)(bm + wm + i * 16 + rbase + r) * 64 + wn + j * 16 + ncol] = acc[i][j][r];
  }
  waitcnt_vm<0>();
  __syncthreads();
  // phase 2: [64,32] @ [256,32]^T, one K=32 MFMA per 16x16 fragment
  int f = detect_f(x0);
  short8 a2[4];
#pragma unroll
  for (int i = 0; i < 4; i++) a2[i] = *(const short8*)&lS[i * 512 + la];
  int colw = cby * 256 + wave * 64;
#pragma unroll
  for (int j = 0; j < 4; j++) {
    short8 b2 = *(const short8*)&lW[(wave * 64 + j * 16) * 32 + la];
#pragma unroll
    for (int i = 0; i < 4; i++) {
      f32x4 c2 = {};
      c2 = __builtin_amdgcn_mfma_f32_16x16x32_bf16(a2[i], b2, c2, 0, 0, 0);
#pragma unroll
      for (int r = 0; r < 4; r++) {
        int col = colw + j * 16 + ncol;
        int row = bm + i * 16 + rbase + r;
        float v = softplus_fast(c2[r] + load_any(dtb, col, f));
        dtf[(size_t)row * 1024 + col] = bs(v);
      }
    }
  }
}

// ---------------- depthwise causal conv(K=4)+SiLU over bf16 xraw -> xt bf16, 8 ch/thread
__global__ __launch_bounds__(256) void conv_silu(
    const short* __restrict__ xraw, const void* __restrict__ cw, const void* __restrict__ cb,
    short* __restrict__ xh, const unsigned int* __restrict__ x0)
{
  int f = detect_f(x0);
  int g = blockIdx.x * 256 + threadIdx.x;      // 524288 = 4096 rows x 128 groups
  int d8 = (g & 127) * 8;
  int row = g >> 7;
  int t = row & (TLEN - 1);
  float a[8];
#pragma unroll
  for (int u = 0; u < 8; u++) a[u] = load_any(cb, d8 + u, f);
#pragma unroll
  for (int k = 0; k < 4; k++) {
    int ts = t - 3 + k;
    if (ts >= 0) {
      short8 xv = *(const short8*)&xraw[(size_t)(row - 3 + k) * 1024 + d8];
#pragma unroll
      for (int u = 0; u < 8; u++)
        a[u] += load_any(cw, (long)(d8 + u) * 4 + k, f) * sb(xv[u]);
    }
  }
  short8 o;
#pragma unroll
  for (int u = 0; u < 8; u++) {
    float s = a[u] / (1.f + fexp2(-a[u] * LOG2E));
    o[u] = bs(s);
  }
  *(short8*)&xh[(size_t)row * 1024 + d8] = o;
}

// ---------------- scan pass 1: per-chunk transfer product P and local state S (bf16)
template <int CLEN>
__global__ __launch_bounds__(256) void scan_pass1(
    const short* __restrict__ dtf, const short* __restrict__ xh,
    const float* __restrict__ ssm, const void* __restrict__ alog,
    short* __restrict__ P, short* __restrict__ S, const unsigned int* __restrict__ x0)
{
  constexpr int NCH = TLEN / CLEN;
  __shared__ float sB[CLEN][NSTATE];
  int f = detect_f(x0);
  int tid = threadIdx.x;
  int c = blockIdx.x % NCH;
  int r = blockIdx.x / NCH;
  int dblk = r & 3, b = r >> 2;
  int d = dblk * 256 + tid;
  int t0 = c * CLEN;
  for (int i = tid; i < CLEN * NSTATE; i += 256) {
    int rr = i >> 4, cc = i & 15;
    sB[rr][cc] = ssm[(size_t)(b * TLEN + t0 + rr) * 64 + 32 + cc];
  }
  float A2[NSTATE], st[NSTATE], Pp[NSTATE];
#pragma unroll
  for (int n = 0; n < NSTATE; n++) {
    A2[n] = -fexp2(load_any(alog, d * NSTATE + n, f) * LOG2E) * LOG2E;
    st[n] = 0.f; Pp[n] = 1.f;
  }
  __syncthreads();
#pragma unroll
  for (int tt = 0; tt < CLEN; tt++) {
    size_t xi = (size_t)(b * TLEN + t0 + tt) * DI + d;
    float dtv = sb(dtf[xi]);
    float xv = sb(xh[xi]);
    float dx = dtv * xv;
#pragma unroll
    for (int n = 0; n < NSTATE; n++) {
      float e = fexp2(dtv * A2[n]);
      st[n] = e * st[n] + dx * sB[tt][n];
      Pp[n] *= e;
    }
  }
  size_t base = ((size_t)(b * NCH + c) * NSTATE) * DI + d;
#pragma unroll
  for (int n = 0; n < NSTATE; n++) {
    P[base + (size_t)n * DI] = bs(Pp[n]);
    S[base + (size_t)n * DI] = bs(st[n]);
  }
}

// ---------------- scan pass 2: combine chunk boundaries; Sin in-place into P (bf16)
__global__ __launch_bounds__(64) void scan_pass2(
    short* __restrict__ P, const short* __restrict__ S, int nchunk)
{
  int idx = blockIdx.x * 64 + threadIdx.x;  // 0..32767 = (b, n, d)
  int d = idx & (DI - 1);
  int n = (idx >> 10) & (NSTATE - 1);
  int b = idx >> 14;
  float s = 0.f;
#pragma clang loop unroll_count(4)
  for (int c = 0; c < nchunk; c++) {
    size_t o = ((size_t)(b * nchunk + c) * NSTATE + n) * DI + d;
    float p = sb(P[o]), sv = sb(S[o]);
    P[o] = bs(s);             // Sin for chunk c
    s = p * s + sv;
  }
}

// ---------------- scan pass 3: full scan + D-skip + pre-silu'd gate -> y bf16
template <int CLEN>
__global__ __launch_bounds__(256) void scan_pass3(
    const short* __restrict__ dtf, const short* __restrict__ xh,
    const float* __restrict__ ssm, const void* __restrict__ alog,
    const short* __restrict__ Sin, const short* __restrict__ gs,
    const void* __restrict__ Dvec, short* __restrict__ yh,
    const unsigned int* __restrict__ x0)
{
  constexpr int NCH = TLEN / CLEN;
  __shared__ float sBC[CLEN][2 * NSTATE];
  int f = detect_f(x0);
  int tid = threadIdx.x;
  int c = blockIdx.x % NCH;
  int r = blockIdx.x / NCH;
  int dblk = r & 3, b = r >> 2;
  int d = dblk * 256 + tid;
  int t0 = c * CLEN;
  for (int i = tid; i < CLEN * 2 * NSTATE; i += 256) {
    int rr = i >> 5, cc = i & 31;
    sBC[rr][cc] = ssm[(size_t)(b * TLEN + t0 + rr) * 64 + 32 + cc];
  }
  float A2[NSTATE], st[NSTATE];
  size_t base = ((size_t)(b * NCH + c) * NSTATE) * DI + d;
#pragma unroll
  for (int n = 0; n < NSTATE; n++) {
    A2[n] = -fexp2(load_any(alog, d * NSTATE + n, f) * LOG2E) * LOG2E;
    st[n] = sb(Sin[base + (size_t)n * DI]);
  }
  float Dd = load_any(Dvec, d, f);
  __syncthreads();
#pragma unroll
  for (int tt = 0; tt < CLEN; tt++) {
    int row = b * TLEN + t0 + tt;
    size_t xi = (size_t)row * DI + d;
    float dtv = sb(dtf[xi]);
    float xv = sb(xh[xi]);
    float dx = dtv * xv;
    float yv = 0.f;
#pragma unroll
    for (int n = 0; n < NSTATE; n++) {
      float e = fexp2(dtv * A2[n]);
      st[n] = e * st[n] + dx * sBC[tt][n];
      yv += st[n] * sBC[tt][NSTATE + n];
    }
    float out = (yv + xv * Dd) * sb(gs[xi]);
    yh[xi] = bs(out);
  }
}

extern "C" void kernel_launch(void* const* d_in, const int* in_sizes, int n_in,
                              void* d_out, int out_size, void* d_ws, size_t ws_size,
                              hipStream_t stream) {
  const void* x    = d_in[0];   // [2,2048,512]
  const void* w1   = d_in[1];   // [2048,512]
  const void* cw   = d_in[2];   // [1024,1,4]
  const void* cb   = d_in[3];   // [1024]
  const void* xw   = d_in[4];   // [64,1024]
  const void* dtw  = d_in[5];   // [1024,32]
  const void* dtb  = d_in[6];   // [1024]
  const void* alog = d_in[7];   // [1024,16]
  const void* Dv   = d_in[8];   // [1024]
  const void* w3   = d_in[9];   // [512,1024]
  const unsigned int* x0 = (const unsigned int*)x;

  char* ws = (char*)d_ws;
  short* xraw = (short*)ws;            ws += (size_t)4096 * 1024 * 2;   // 8.39 MB
  short* gs_h = (short*)ws;            ws += (size_t)4096 * 1024 * 2;   // 8.39 MB
  short* xt_h = (short*)ws;            ws += (size_t)4096 * 1024 * 2;   // 8.39 MB
  float* ssm  = (float*)ws;            ws += (size_t)4096 * 64 * 4;     // 1.05 MB
  short* y_h  = (short*)ws;            ws += (size_t)4096 * 1024 * 2;   // 8.39 MB
  short* dtf  = (short*)ws;            ws += (size_t)4096 * 1024 * 2;   // 8.39 MB
  short* smH  = (short*)ws;            ws += (size_t)622592 * 2;        // 1.25 MB
  short* sdH  = (short*)ws;            ws += (size_t)131072 * 2;        // 0.26 MB (unused, kept for layout)
  char*  R    = ws;                                                      // staging / P|S
  (void)sdH;

  size_t fixed = (size_t)(ws - (char*)d_ws);
  int nchunk = 64;    // CLEN=32: 512 blocks for pass1/3; pass2 chain 64 iters
  while (nchunk > 32) {
    size_t region = (size_t)131072 * nchunk;      // P+S bf16
    if (region < 7536640) region = 7536640;       // cast staging floor
    if (fixed + region <= ws_size) break;
    nchunk >>= 1;
  }
  int clen = TLEN / nchunk;

  short* bigH = (short*)R;                       // x @0, w1 @2097152 (hi)
  short* P    = (short*)R;                       // after in_proj: P|S (bf16)
  short* S    = (short*)(R + (size_t)65536 * nchunk);

  cast_h<<<dim3(3680), 256, 0, stream>>>(x, w1, xw, w3, dtw, bigH, smH);
  // in_proj: [4096,512] x [2048,512]^T -> xraw bf16 + silu(gate) bf16 (MODE 3)
  gemm_mf<128, 128, 3><<<dim3(32, 16), 256, 0, stream>>>(
      bigH, bigH + 2097152, nullptr, 512, 512, 512, 2048, nullptr, x0, xraw, gs_h);
  // conv + silu -> xt bf16 (8 channels/thread, short8)
  conv_silu<<<dim3(2048), 256, 0, stream>>>(xraw, cw, cb, xt_h, x0);
  // fused x_proj + dt_proj: ssm fp32 (cols 32..64) + dtf bf16
  xdt_gemm<<<dim3(64, 4), 256, 0, stream>>>(
      xt_h, smH, smH + 589824, ssm, dtb, x0, dtf);
  // chunked linear-recurrence scan -> y bf16
  dim3 sg(8 * nchunk);
  switch (clen) {
    case 16:
      scan_pass1<16><<<sg, 256, 0, stream>>>(dtf, xt_h, ssm, alog, P, S, x0);
      scan_pass2<<<dim3(512), 64, 0, stream>>>(P, S, nchunk);
      scan_pass3<16><<<sg, 256, 0, stream>>>(dtf, xt_h, ssm, alog, P, gs_h, Dv, y_h, x0);
      break;
    case 32:
      scan_pass1<32><<<sg, 256, 0, stream>>>(dtf, xt_h, ssm, alog, P, S, x0);
      scan_pass2<<<dim3(512), 64, 0, stream>>>(P, S, nchunk);
      scan_pass3<32><<<sg, 256, 0, stream>>>(dtf, xt_h, ssm, alog, P, gs_h, Dv, y_h, x0);
      break;
    default:
      scan_pass1<64><<<sg, 256, 0, stream>>>(dtf, xt_h, ssm, alog, P, S, x0);
      scan_pass2<<<dim3(512), 64, 0, stream>>>(P, S, nchunk);
      scan_pass3<64><<<sg, 256, 0, stream>>>(dtf, xt_h, ssm, alog, P, gs_h, Dv, y_h, x0);
      break;
  }
  // out_proj: [4096,1024] x [512,1024]^T -> d_out fp32 (128x64 tile, 8 MFMA/iter)
  gemm_mf<128, 64, 0><<<dim3(32, 8), 256, 0, stream>>>(
      y_h, smH + 65536, (float*)d_out, 1024, 1024, 1024, 512, nullptr, x0, nullptr, nullptr);
}

// Round 2
// 235.083 us; speedup vs baseline: 1.0472x; 1.0472x over previous
//
#include <hip/hip_runtime.h>
#include <hip/hip_bf16.h>
#include <math.h>

typedef __hip_bfloat16 bf16t;
typedef __attribute__((ext_vector_type(8))) short short8;
typedef __attribute__((ext_vector_type(4))) float f32x4;

#define DI 1024
#define NSTATE 16
#define TLEN 2048
#define LOG2E 1.4426950408889634f

__device__ __forceinline__ float b2f(bf16t v) { return __bfloat162float(v); }
__device__ __forceinline__ bf16t f2b(float v) { return __float2bfloat16(v); }
__device__ __forceinline__ float fexp2(float x) { return __builtin_amdgcn_exp2f(x); }
__device__ __forceinline__ float flog2(float x) { return __builtin_amdgcn_logf(x); }
__device__ __forceinline__ float softplus_fast(float v) {
  return (v > 20.f) ? v : flog2(1.f + fexp2(v * LOG2E)) * (1.f / LOG2E);
}
__device__ __forceinline__ short bs(float v) { bf16t h = f2b(v); return *(short*)&h; }
__device__ __forceinline__ float sb(short v) { return b2f(*(bf16t*)&v); }

// wave-ballot dtype detect on first 64 words of x: 1 = fp32 inputs, 0 = bf16
__device__ __forceinline__ int detect_f(const unsigned int* __restrict__ x0) {
  unsigned int w = x0[threadIdx.x & 63];
  int e = (w >> 7) & 0xFF;
  unsigned long long m = __ballot(e >= 110 && e <= 135);
  return (__popcll(m) < 32) ? 1 : 0;
}

// runtime-dtype load for RAW INPUTS: f=1 -> fp32, f=0 -> bf16
__device__ __forceinline__ float load_any(const void* s, long i, int f) {
  return f ? ((const float*)s)[i] : b2f(((const bf16t*)s)[i]);
}

__device__ __forceinline__ void async16(const void* g, void* l) {
  __builtin_amdgcn_global_load_lds(
      (const __attribute__((address_space(1))) unsigned int*)g,
      (__attribute__((address_space(3))) unsigned int*)l, 16, 0, 0);
}

template <int N> __device__ __forceinline__ void waitcnt_vm() {
  if constexpr (N == 0)      asm volatile("s_waitcnt vmcnt(0)" ::: "memory");
  else if constexpr (N == 2) asm volatile("s_waitcnt vmcnt(2)" ::: "memory");
  else if constexpr (N == 4) asm volatile("s_waitcnt vmcnt(4)" ::: "memory");
}
__device__ __forceinline__ void raw_barrier() { asm volatile("s_barrier" ::: "memory"); }

// ---------------- bf16 cast of all 5 GEMM matrices (hi planes only)
// big (aliased over P/S): x[0,2097152) w1[2097152,3145728)
// small (persistent): xw[0,65536) w3[65536,589824) dtw[589824,622592)
__global__ __launch_bounds__(256) void cast_h(
    const void* __restrict__ x, const void* __restrict__ w1,
    const void* __restrict__ xw, const void* __restrict__ w3, const void* __restrict__ dtw,
    short* __restrict__ bigH, short* __restrict__ smallH)
{
  int f = detect_f((const unsigned int*)x);
  int i0 = (blockIdx.x * 256 + threadIdx.x) * 4;
#pragma unroll
  for (int q = 0; q < 4; q++) {
    int i = i0 + q;
    if (i >= 3768320) return;
    if (i < 3145728) {
      float v = (i < 2097152) ? load_any(x, i, f) : load_any(w1, i - 2097152, f);
      bigH[i] = bs(v);
    } else {
      int j = i - 3145728;
      float v;
      if (j < 65536)       v = load_any(xw, j, f);
      else if (j < 589824) v = load_any(w3, j - 65536, f);
      else                 v = load_any(dtw, j - 589824, f);
      smallH[j] = bs(v);
    }
  }
}

// ---------------- bf16 MFMA GEMM, double-buffered K-loop: C[M,N] = A[M,K] * B[N,K]^T
// MODE 0: fp32 C. MODE 1: +bias softplus -> bf16 outH. MODE 2: fp32 C + bf16 cols<32.
// MODE 3 (in_proj): cols<1024 -> bf16 outH (raw); cols>=1024 -> silu -> bf16 out2.
template <int BM, int BN, int MODE>
__global__ __launch_bounds__(256) void gemm_mf(
    const short* __restrict__ Ah, const short* __restrict__ Bh,
    float* __restrict__ C, int K, int lda, int ldb, int ldc,
    const void* __restrict__ bias, const unsigned int* __restrict__ x0,
    short* __restrict__ outH, short* __restrict__ out2)
{
  constexpr int NFM = BM / 32, NFN = BN / 32;
  constexpr int SA = BM / 64, SB = BN / 64;
  constexpr int NL = SA + SB;
  __shared__ __align__(16) short lA[2 * BM * 32];
  __shared__ __align__(16) short lB[2 * BN * 32];
  int tid = threadIdx.x;
  int lane = tid & 63, wave = tid >> 6;
  int bm = blockIdx.x * BM, bn = blockIdx.y * BN;
  int wm = (wave & 1) * (BM / 2), wn = (wave >> 1) * (BN / 2);
  f32x4 acc[NFM][NFN] = {};
  int r0 = tid >> 2, kp = (tid & 3) * 8;
  const short* pA = Ah + (size_t)(bm + r0) * lda + kp;
  const short* pB = Bh + (size_t)(bn + r0) * ldb + kp;
  int ldsOff = tid * 8;
  int la = (lane & 15) * 32 + (lane >> 4) * 8;
  int nIter = K / 32;

  auto stage = [&](int kk, int b) {
    int off = kk * 32;
#pragma unroll
    for (int s = 0; s < SA; s++)
      async16(pA + off + (size_t)s * 64 * lda, &lA[b * BM * 32 + ldsOff + s * 64 * 32]);
#pragma unroll
    for (int s = 0; s < SB; s++)
      async16(pB + off + (size_t)s * 64 * ldb, &lB[b * BN * 32 + ldsOff + s * 64 * 32]);
  };

  stage(0, 0);
  for (int kk = 0; kk < nIter; kk++) {
    int cur = kk & 1;
    bool more = (kk + 1 < nIter);
    if (more) stage(kk + 1, cur ^ 1);
    if (more) waitcnt_vm<NL>(); else waitcnt_vm<0>();
    raw_barrier();
    short8 af[NFM], bf[NFN];
#pragma unroll
    for (int i = 0; i < NFM; i++)
      af[i] = *(const short8*)&lA[cur * BM * 32 + (wm + i * 16) * 32 + la];
#pragma unroll
    for (int j = 0; j < NFN; j++)
      bf[j] = *(const short8*)&lB[cur * BN * 32 + (wn + j * 16) * 32 + la];
#pragma unroll
    for (int i = 0; i < NFM; i++)
#pragma unroll
      for (int j = 0; j < NFN; j++)
        acc[i][j] = __builtin_amdgcn_mfma_f32_16x16x32_bf16(af[i], bf[j], acc[i][j], 0, 0, 0);
    raw_barrier();
  }
  int f = (MODE == 1) ? detect_f(x0) : 0;
  int rbase = (lane >> 4) * 4, ncol = lane & 15;
#pragma unroll
  for (int i = 0; i < NFM; i++)
#pragma unroll
    for (int j = 0; j < NFN; j++)
#pragma unroll
      for (int r = 0; r < 4; r++) {
        int m = bm + wm + i * 16 + rbase + r;
        int n = bn + wn + j * 16 + ncol;
        float v = acc[i][j][r];
        if constexpr (MODE == 1) {
          v = softplus_fast(v + load_any(bias, n, f));
          outH[(size_t)m * ldc + n] = bs(v);
        } else if constexpr (MODE == 3) {
          if (n < 1024) {
            outH[(size_t)m * 1024 + n] = bs(v);                       // raw x half
          } else {
            float gv = v / (1.f + fexp2(-v * LOG2E));                 // silu(gate)
            out2[(size_t)m * 1024 + (n - 1024)] = bs(gv);
          }
        } else {
          C[(size_t)m * ldc + n] = v;
          if constexpr (MODE == 2) {
            if (n < 32) outH[(size_t)m * 32 + n] = bs(v);
          }
        }
      }
}

// ---------------- depthwise causal conv(K=4)+SiLU over bf16 xraw -> xt bf16, 8 ch/thread
__global__ __launch_bounds__(256) void conv_silu(
    const short* __restrict__ xraw, const void* __restrict__ cw, const void* __restrict__ cb,
    short* __restrict__ xh, const unsigned int* __restrict__ x0)
{
  int f = detect_f(x0);
  int g = blockIdx.x * 256 + threadIdx.x;      // 524288 = 4096 rows x 128 groups
  int d8 = (g & 127) * 8;
  int row = g >> 7;
  int t = row & (TLEN - 1);
  float a[8];
#pragma unroll
  for (int u = 0; u < 8; u++) a[u] = load_any(cb, d8 + u, f);
#pragma unroll
  for (int k = 0; k < 4; k++) {
    int ts = t - 3 + k;
    if (ts >= 0) {
      short8 xv = *(const short8*)&xraw[(size_t)(row - 3 + k) * 1024 + d8];
#pragma unroll
      for (int u = 0; u < 8; u++)
        a[u] += load_any(cw, (long)(d8 + u) * 4 + k, f) * sb(xv[u]);
    }
  }
  short8 o;
#pragma unroll
  for (int u = 0; u < 8; u++) {
    float s = a[u] / (1.f + fexp2(-a[u] * LOG2E));
    o[u] = bs(s);
  }
  *(short8*)&xh[(size_t)row * 1024 + d8] = o;
}

// ---------------- scan pass 1: per-chunk transfer product P and local state S (bf16)
template <int CLEN>
__global__ __launch_bounds__(256) void scan_pass1(
    const short* __restrict__ dtf, const short* __restrict__ xh,
    const float* __restrict__ ssm, const void* __restrict__ alog,
    short* __restrict__ P, short* __restrict__ S, const unsigned int* __restrict__ x0)
{
  constexpr int NCH = TLEN / CLEN;
  __shared__ float sB[CLEN][NSTATE];
  int f = detect_f(x0);
  int tid = threadIdx.x;
  int c = blockIdx.x % NCH;
  int r = blockIdx.x / NCH;
  int dblk = r & 3, b = r >> 2;
  int d = dblk * 256 + tid;
  int t0 = c * CLEN;
  for (int i = tid; i < CLEN * NSTATE; i += 256) {
    int rr = i >> 4, cc = i & 15;
    sB[rr][cc] = ssm[(size_t)(b * TLEN + t0 + rr) * 64 + 32 + cc];
  }
  float A2[NSTATE], st[NSTATE], Pp[NSTATE];
#pragma unroll
  for (int n = 0; n < NSTATE; n++) {
    A2[n] = -fexp2(load_any(alog, d * NSTATE + n, f) * LOG2E) * LOG2E;
    st[n] = 0.f; Pp[n] = 1.f;
  }
  __syncthreads();
#pragma unroll
  for (int tt = 0; tt < CLEN; tt++) {
    size_t xi = (size_t)(b * TLEN + t0 + tt) * DI + d;
    float dtv = sb(dtf[xi]);
    float xv = sb(xh[xi]);
    float dx = dtv * xv;
#pragma unroll
    for (int n = 0; n < NSTATE; n++) {
      float e = fexp2(dtv * A2[n]);
      st[n] = e * st[n] + dx * sB[tt][n];
      Pp[n] *= e;
    }
  }
  size_t base = ((size_t)(b * NCH + c) * NSTATE) * DI + d;
#pragma unroll
  for (int n = 0; n < NSTATE; n++) {
    P[base + (size_t)n * DI] = bs(Pp[n]);
    S[base + (size_t)n * DI] = bs(st[n]);
  }
}

// ---------------- scan pass 2: combine chunk boundaries; Sin in-place into P (bf16)
__global__ __launch_bounds__(64) void scan_pass2(
    short* __restrict__ P, const short* __restrict__ S, int nchunk)
{
  int idx = blockIdx.x * 64 + threadIdx.x;  // 0..32767 = (b, n, d)
  int d = idx & (DI - 1);
  int n = (idx >> 10) & (NSTATE - 1);
  int b = idx >> 14;
  float s = 0.f;
#pragma clang loop unroll_count(4)
  for (int c = 0; c < nchunk; c++) {
    size_t o = ((size_t)(b * nchunk + c) * NSTATE + n) * DI + d;
    float p = sb(P[o]), sv = sb(S[o]);
    P[o] = bs(s);             // Sin for chunk c
    s = p * s + sv;
  }
}

// ---------------- scan pass 3: full scan + D-skip + pre-silu'd gate -> y bf16
template <int CLEN>
__global__ __launch_bounds__(256) void scan_pass3(
    const short* __restrict__ dtf, const short* __restrict__ xh,
    const float* __restrict__ ssm, const void* __restrict__ alog,
    const short* __restrict__ Sin, const short* __restrict__ gs,
    const void* __restrict__ Dvec, short* __restrict__ yh,
    const unsigned int* __restrict__ x0)
{
  constexpr int NCH = TLEN / CLEN;
  __shared__ float sBC[CLEN][2 * NSTATE];
  int f = detect_f(x0);
  int tid = threadIdx.x;
  int c = blockIdx.x % NCH;
  int r = blockIdx.x / NCH;
  int dblk = r & 3, b = r >> 2;
  int d = dblk * 256 + tid;
  int t0 = c * CLEN;
  for (int i = tid; i < CLEN * 2 * NSTATE; i += 256) {
    int rr = i >> 5, cc = i & 31;
    sBC[rr][cc] = ssm[(size_t)(b * TLEN + t0 + rr) * 64 + 32 + cc];
  }
  float A2[NSTATE], st[NSTATE];
  size_t base = ((size_t)(b * NCH + c) * NSTATE) * DI + d;
#pragma unroll
  for (int n = 0; n < NSTATE; n++) {
    A2[n] = -fexp2(load_any(alog, d * NSTATE + n, f) * LOG2E) * LOG2E;
    st[n] = sb(Sin[base + (size_t)n * DI]);
  }
  float Dd = load_any(Dvec, d, f);
  __syncthreads();
#pragma unroll
  for (int tt = 0; tt < CLEN; tt++) {
    int row = b * TLEN + t0 + tt;
    size_t xi = (size_t)row * DI + d;
    float dtv = sb(dtf[xi]);
    float xv = sb(xh[xi]);
    float dx = dtv * xv;
    float yv = 0.f;
#pragma unroll
    for (int n = 0; n < NSTATE; n++) {
      float e = fexp2(dtv * A2[n]);
      st[n] = e * st[n] + dx * sBC[tt][n];
      yv += st[n] * sBC[tt][NSTATE + n];
    }
    float out = (yv + xv * Dd) * sb(gs[xi]);
    yh[xi] = bs(out);
  }
}

extern "C" void kernel_launch(void* const* d_in, const int* in_sizes, int n_in,
                              void* d_out, int out_size, void* d_ws, size_t ws_size,
                              hipStream_t stream) {
  const void* x    = d_in[0];   // [2,2048,512]
  const void* w1   = d_in[1];   // [2048,512]
  const void* cw   = d_in[2];   // [1024,1,4]
  const void* cb   = d_in[3];   // [1024]
  const void* xw   = d_in[4];   // [64,1024]
  const void* dtw  = d_in[5];   // [1024,32]
  const void* dtb  = d_in[6];   // [1024]
  const void* alog = d_in[7];   // [1024,16]
  const void* Dv   = d_in[8];   // [1024]
  const void* w3   = d_in[9];   // [512,1024]
  const unsigned int* x0 = (const unsigned int*)x;

  char* ws = (char*)d_ws;
  short* xraw = (short*)ws;            ws += (size_t)4096 * 1024 * 2;   // 8.39 MB
  short* gs_h = (short*)ws;            ws += (size_t)4096 * 1024 * 2;   // 8.39 MB
  short* xt_h = (short*)ws;            ws += (size_t)4096 * 1024 * 2;   // 8.39 MB
  float* ssm  = (float*)ws;            ws += (size_t)4096 * 64 * 4;     // 1.05 MB
  short* y_h  = (short*)ws;            ws += (size_t)4096 * 1024 * 2;   // 8.39 MB
  short* dtf  = (short*)ws;            ws += (size_t)4096 * 1024 * 2;   // 8.39 MB
  short* smH  = (short*)ws;            ws += (size_t)622592 * 2;        // 1.25 MB
  short* sdH  = (short*)ws;            ws += (size_t)131072 * 2;        // 0.26 MB
  char*  R    = ws;                                                      // staging / P|S

  size_t fixed = (size_t)(ws - (char*)d_ws);
  int nchunk = 64;    // CLEN=32: 512 blocks for pass1/3; pass2 chain 64 iters
  while (nchunk > 32) {
    size_t region = (size_t)131072 * nchunk;      // P+S bf16
    if (region < 7536640) region = 7536640;       // cast staging floor
    if (fixed + region <= ws_size) break;
    nchunk >>= 1;
  }
  int clen = TLEN / nchunk;

  short* bigH = (short*)R;                       // x @0, w1 @2097152 (hi)
  short* P    = (short*)R;                       // after in_proj: P|S (bf16)
  short* S    = (short*)(R + (size_t)65536 * nchunk);

  cast_h<<<dim3(3680), 256, 0, stream>>>(x, w1, xw, w3, dtw, bigH, smH);
  // in_proj: [4096,512] x [2048,512]^T -> xraw bf16 + silu(gate) bf16 (MODE 3)
  gemm_mf<128, 128, 3><<<dim3(32, 16), 256, 0, stream>>>(
      bigH, bigH + 2097152, nullptr, 512, 512, 512, 2048, nullptr, x0, xraw, gs_h);
  // conv + silu -> xt bf16 (8 channels/thread, short8)
  conv_silu<<<dim3(2048), 256, 0, stream>>>(xraw, cw, cb, xt_h, x0);
  // x_proj: [4096,1024] x [64,1024]^T -> ssm fp32 + dt-slice bf16
  gemm_mf<64, 64, 2><<<dim3(64, 1), 256, 0, stream>>>(
      xt_h, smH, ssm, 1024, 1024, 1024, 64, nullptr, x0, sdH, nullptr);
  // dt: [4096,32] x [1024,32]^T + bias + softplus -> dtf bf16
  gemm_mf<64, 64, 1><<<dim3(64, 16), 256, 0, stream>>>(
      sdH, smH + 589824, nullptr, 32, 32, 32, 1024, dtb, x0, dtf, nullptr);
  // chunked linear-recurrence scan -> y bf16
  dim3 sg(8 * nchunk);
  switch (clen) {
    case 16:
      scan_pass1<16><<<sg, 256, 0, stream>>>(dtf, xt_h, ssm, alog, P, S, x0);
      scan_pass2<<<dim3(512), 64, 0, stream>>>(P, S, nchunk);
      scan_pass3<16><<<sg, 256, 0, stream>>>(dtf, xt_h, ssm, alog, P, gs_h, Dv, y_h, x0);
      break;
    case 32:
      scan_pass1<32><<<sg, 256, 0, stream>>>(dtf, xt_h, ssm, alog, P, S, x0);
      scan_pass2<<<dim3(512), 64, 0, stream>>>(P, S, nchunk);
      scan_pass3<32><<<sg, 256, 0, stream>>>(dtf, xt_h, ssm, alog, P, gs_h, Dv, y_h, x0);
      break;
    default:
      scan_pass1<64><<<sg, 256, 0, stream>>>(dtf, xt_h, ssm, alog, P, S, x0);
      scan_pass2<<<dim3(512), 64, 0, stream>>>(P, S, nchunk);
      scan_pass3<64><<<sg, 256, 0, stream>>>(dtf, xt_h, ssm, alog, P, gs_h, Dv, y_h, x0);
      break;
  }
  // out_proj: [4096,1024] x [512,1024]^T -> d_out fp32
  gemm_mf<64, 64, 0><<<dim3(64, 8), 256, 0, stream>>>(
      y_h, smH + 65536, (float*)d_out, 1024, 1024, 1024, 512, nullptr, x0, nullptr, nullptr);
}

// Round 4
// 224.780 us; speedup vs baseline: 1.0952x; 1.0458x over previous
//
#include <hip/hip_runtime.h>
#include <hip/hip_bf16.h>
#include <math.h>

typedef __hip_bfloat16 bf16t;
typedef __attribute__((ext_vector_type(8))) short short8;
typedef __attribute__((ext_vector_type(4))) float f32x4;

#define DI 1024
#define NSTATE 16
#define TLEN 2048
#define LOG2E 1.4426950408889634f

__device__ __forceinline__ float b2f(bf16t v) { return __bfloat162float(v); }
__device__ __forceinline__ bf16t f2b(float v) { return __float2bfloat16(v); }
__device__ __forceinline__ float fexp2(float x) { return __builtin_amdgcn_exp2f(x); }
__device__ __forceinline__ float flog2(float x) { return __builtin_amdgcn_logf(x); }
__device__ __forceinline__ float softplus_fast(float v) {
  return (v > 20.f) ? v : flog2(1.f + fexp2(v * LOG2E)) * (1.f / LOG2E);
}
__device__ __forceinline__ short bs(float v) { bf16t h = f2b(v); return *(short*)&h; }
__device__ __forceinline__ float sb(short v) { return b2f(*(bf16t*)&v); }

// wave-ballot dtype detect on first 64 words of x: 1 = fp32 inputs, 0 = bf16
__device__ __forceinline__ int detect_f(const unsigned int* __restrict__ x0) {
  unsigned int w = x0[threadIdx.x & 63];
  int e = (w >> 7) & 0xFF;
  unsigned long long m = __ballot(e >= 110 && e <= 135);
  return (__popcll(m) < 32) ? 1 : 0;
}

// runtime-dtype load for RAW INPUTS: f=1 -> fp32, f=0 -> bf16
__device__ __forceinline__ float load_any(const void* s, long i, int f) {
  return f ? ((const float*)s)[i] : b2f(((const bf16t*)s)[i]);
}

__device__ __forceinline__ void async16(const void* g, void* l) {
  __builtin_amdgcn_global_load_lds(
      (const __attribute__((address_space(1))) unsigned int*)g,
      (__attribute__((address_space(3))) unsigned int*)l, 16, 0, 0);
}

template <int N> __device__ __forceinline__ void waitcnt_vm() {
  if constexpr (N == 0)      asm volatile("s_waitcnt vmcnt(0)" ::: "memory");
  else if constexpr (N == 2) asm volatile("s_waitcnt vmcnt(2)" ::: "memory");
  else if constexpr (N == 4) asm volatile("s_waitcnt vmcnt(4)" ::: "memory");
  else if constexpr (N == 6) asm volatile("s_waitcnt vmcnt(6)" ::: "memory");
}
__device__ __forceinline__ void raw_barrier() { asm volatile("s_barrier" ::: "memory"); }

// ---------------- bf16 cast of all 5 GEMM matrices (hi planes only)
// big (aliased over P/S): x[0,2097152) w1[2097152,3145728)
// small (persistent): xw[0,65536) w3[65536,589824) dtw[589824,622592)
__global__ __launch_bounds__(256) void cast_h(
    const void* __restrict__ x, const void* __restrict__ w1,
    const void* __restrict__ xw, const void* __restrict__ w3, const void* __restrict__ dtw,
    short* __restrict__ bigH, short* __restrict__ smallH)
{
  int f = detect_f((const unsigned int*)x);
  int i0 = (blockIdx.x * 256 + threadIdx.x) * 4;
#pragma unroll
  for (int q = 0; q < 4; q++) {
    int i = i0 + q;
    if (i >= 3768320) return;
    if (i < 3145728) {
      float v = (i < 2097152) ? load_any(x, i, f) : load_any(w1, i - 2097152, f);
      bigH[i] = bs(v);
    } else {
      int j = i - 3145728;
      float v;
      if (j < 65536)       v = load_any(xw, j, f);
      else if (j < 589824) v = load_any(w3, j - 65536, f);
      else                 v = load_any(dtw, j - 589824, f);
      smallH[j] = bs(v);
    }
  }
}

// ---------------- bf16 MFMA GEMM, double-buffered K-loop: C[M,N] = A[M,K] * B[N,K]^T
// MODE 0: fp32 C. MODE 3 (in_proj): cols<1024 -> bf16 outH; cols>=1024 -> silu -> bf16 out2.
template <int BM, int BN, int MODE>
__global__ __launch_bounds__(256) void gemm_mf(
    const short* __restrict__ Ah, const short* __restrict__ Bh,
    float* __restrict__ C, int K, int lda, int ldb, int ldc,
    const void* __restrict__ bias, const unsigned int* __restrict__ x0,
    short* __restrict__ outH, short* __restrict__ out2)
{
  constexpr int NFM = BM / 32, NFN = BN / 32;
  constexpr int SA = BM / 64, SB = BN / 64;
  constexpr int NL = SA + SB;
  __shared__ __align__(16) short lA[2 * BM * 32];
  __shared__ __align__(16) short lB[2 * BN * 32];
  int tid = threadIdx.x;
  int lane = tid & 63, wave = tid >> 6;
  int bm = blockIdx.x * BM, bn = blockIdx.y * BN;
  int wm = (wave & 1) * (BM / 2), wn = (wave >> 1) * (BN / 2);
  f32x4 acc[NFM][NFN] = {};
  int r0 = tid >> 2, kp = (tid & 3) * 8;
  const short* pA = Ah + (size_t)(bm + r0) * lda + kp;
  const short* pB = Bh + (size_t)(bn + r0) * ldb + kp;
  int ldsOff = tid * 8;
  int la = (lane & 15) * 32 + (lane >> 4) * 8;
  int nIter = K / 32;

  auto stage = [&](int kk, int b) {
    int off = kk * 32;
#pragma unroll
    for (int s = 0; s < SA; s++)
      async16(pA + off + (size_t)s * 64 * lda, &lA[b * BM * 32 + ldsOff + s * 64 * 32]);
#pragma unroll
    for (int s = 0; s < SB; s++)
      async16(pB + off + (size_t)s * 64 * ldb, &lB[b * BN * 32 + ldsOff + s * 64 * 32]);
  };

  stage(0, 0);
  for (int kk = 0; kk < nIter; kk++) {
    int cur = kk & 1;
    bool more = (kk + 1 < nIter);
    if (more) stage(kk + 1, cur ^ 1);
    if (more) waitcnt_vm<NL>(); else waitcnt_vm<0>();
    raw_barrier();
    short8 af[NFM], bf[NFN];
#pragma unroll
    for (int i = 0; i < NFM; i++)
      af[i] = *(const short8*)&lA[cur * BM * 32 + (wm + i * 16) * 32 + la];
#pragma unroll
    for (int j = 0; j < NFN; j++)
      bf[j] = *(const short8*)&lB[cur * BN * 32 + (wn + j * 16) * 32 + la];
#pragma unroll
    for (int i = 0; i < NFM; i++)
#pragma unroll
      for (int j = 0; j < NFN; j++)
        acc[i][j] = __builtin_amdgcn_mfma_f32_16x16x32_bf16(af[i], bf[j], acc[i][j], 0, 0, 0);
    raw_barrier();
  }
  int rbase = (lane >> 4) * 4, ncol = lane & 15;
#pragma unroll
  for (int i = 0; i < NFM; i++)
#pragma unroll
    for (int j = 0; j < NFN; j++)
#pragma unroll
      for (int r = 0; r < 4; r++) {
        int m = bm + wm + i * 16 + rbase + r;
        int n = bn + wn + j * 16 + ncol;
        float v = acc[i][j][r];
        if constexpr (MODE == 3) {
          if (n < 1024) {
            outH[(size_t)m * 1024 + n] = bs(v);                       // raw x half
          } else {
            float gv = v / (1.f + fexp2(-v * LOG2E));                 // silu(gate)
            out2[(size_t)m * 1024 + (n - 1024)] = bs(gv);
          }
        } else {
          C[(size_t)m * ldc + n] = v;
        }
      }
}

// ---------------- fused x_proj + dt_proj (R1-validated variant)
// Phase 1: per block, rows [bm,bm+64): S_tile[64,64] = xt @ xw^T (K=1024, 4-deep ring).
//   blockIdx.y in [0,4) replicates phase 1 (0.5 GFLOP each) so the chip is full.
//   cby==0, wn==32 waves write ssm fp32 cols 32..64; wn==0 waves park cols 0..32 in LDS (bf16).
// Phase 2: dt = softplus(S_tile[:,0:32] @ dtw^T + dtb) for col-block cby (256 cols), K=32 MFMA
//   from LDS; dtw tile staged after the first 3 K-tiles (drains by kk=2's vmcnt).
__global__ __launch_bounds__(256) void xdt_gemm(
    const short* __restrict__ Ah,   // xt_h [4096,1024] bf16
    const short* __restrict__ Bh,   // xw   [64,1024]  bf16
    const short* __restrict__ Wdt,  // dtw  [1024,32]  bf16
    float* __restrict__ ssm,        // [4096,64] fp32 (cols 32..64 written)
    const void* __restrict__ dtb, const unsigned int* __restrict__ x0,
    short* __restrict__ dtf)        // [4096,1024] bf16
{
  __shared__ __align__(16) short lA[4 * 64 * 32];
  __shared__ __align__(16) short lB[4 * 64 * 32];
  __shared__ __align__(16) short lW[256 * 32];
  __shared__ __align__(16) short lS[64 * 32];
  int tid = threadIdx.x;
  int lane = tid & 63, wave = tid >> 6;
  int bm = blockIdx.x * 64;
  int cby = blockIdx.y;
  int wm = (wave & 1) * 32, wn = (wave >> 1) * 32;
  f32x4 acc[2][2] = {};
  int r0 = tid >> 2, kp = (tid & 3) * 8;
  const short* pA = Ah + (size_t)(bm + r0) * 1024 + kp;
  const short* pB = Bh + (size_t)r0 * 1024 + kp;
  int ldsOff = tid * 8;
  int la = (lane & 15) * 32 + (lane >> 4) * 8;

  auto stg = [&](int kk, int b) {
    async16(pA + kk * 32, &lA[b * 2048 + ldsOff]);
    async16(pB + kk * 32, &lB[b * 2048 + ldsOff]);
  };
  // prologue: 3 K-tiles ahead, then the phase-2 dtw tile
  stg(0, 0); stg(1, 1); stg(2, 2);
#pragma unroll
  for (int q = 0; q < 4; q++)
    async16(Wdt + (size_t)cby * 8192 + (q * 256 + tid) * 8, &lW[(q * 256 + tid) * 8]);

  for (int kk = 0; kk < 32; kk++) {
    int cur = kk & 3;
    if (kk + 3 < 32) {
      stg(kk + 3, (kk + 3) & 3);
      waitcnt_vm<6>();
    } else if (kk + 2 < 32) waitcnt_vm<4>();
    else if (kk + 1 < 32)   waitcnt_vm<2>();
    else                    waitcnt_vm<0>();
    raw_barrier();
    short8 af[2], bf2[2];
#pragma unroll
    for (int i = 0; i < 2; i++)
      af[i] = *(const short8*)&lA[cur * 2048 + (wm + i * 16) * 32 + la];
#pragma unroll
    for (int j = 0; j < 2; j++)
      bf2[j] = *(const short8*)&lB[cur * 2048 + (wn + j * 16) * 32 + la];
#pragma unroll
    for (int i = 0; i < 2; i++)
#pragma unroll
      for (int j = 0; j < 2; j++)
        acc[i][j] = __builtin_amdgcn_mfma_f32_16x16x32_bf16(af[i], bf2[j], acc[i][j], 0, 0, 0);
    raw_barrier();
  }
  int rbase = (lane >> 4) * 4, ncol = lane & 15;
  if (wn == 0) {
    // dt-input slice (cols 0..32) -> lS bf16 (same rounding point as old sdH)
#pragma unroll
    for (int i = 0; i < 2; i++)
#pragma unroll
      for (int j = 0; j < 2; j++)
#pragma unroll
        for (int r = 0; r < 4; r++)
          lS[(wm + i * 16 + rbase + r) * 32 + j * 16 + ncol] = bs(acc[i][j][r]);
  } else if (cby == 0) {
    // B,C cols (32..64) -> ssm fp32, written once (cby==0)
#pragma unroll
    for (int i = 0; i < 2; i++)
#pragma unroll
      for (int j = 0; j < 2; j++)
#pragma unroll
        for (int r = 0; r < 4; r++)
          ssm[(size_t)(bm + wm + i * 16 + rbase + r) * 64 + wn + j * 16 + ncol] = acc[i][j][r];
  }
  waitcnt_vm<0>();
  __syncthreads();
  // phase 2: [64,32] @ [256,32]^T, one K=32 MFMA per 16x16 fragment
  int f = detect_f(x0);
  short8 a2[4];
#pragma unroll
  for (int i = 0; i < 4; i++) a2[i] = *(const short8*)&lS[i * 512 + la];
  int colw = cby * 256 + wave * 64;
#pragma unroll
  for (int j = 0; j < 4; j++) {
    short8 b2 = *(const short8*)&lW[(wave * 64 + j * 16) * 32 + la];
#pragma unroll
    for (int i = 0; i < 4; i++) {
      f32x4 c2 = {};
      c2 = __builtin_amdgcn_mfma_f32_16x16x32_bf16(a2[i], b2, c2, 0, 0, 0);
#pragma unroll
      for (int r = 0; r < 4; r++) {
        int col = colw + j * 16 + ncol;
        int row = bm + i * 16 + rbase + r;
        float v = softplus_fast(c2[r] + load_any(dtb, col, f));
        dtf[(size_t)row * 1024 + col] = bs(v);
      }
    }
  }
}

// ---------------- depthwise causal conv(K=4)+SiLU over bf16 xraw -> xt bf16
__global__ __launch_bounds__(256) void conv_silu(
    const short* __restrict__ xraw, const void* __restrict__ cw, const void* __restrict__ cb,
    short* __restrict__ xh, const unsigned int* __restrict__ x0)
{
  int f = detect_f(x0);
  int idx = blockIdx.x * 256 + threadIdx.x;
  int d = idx & (DI - 1);
  int row = idx >> 10;
  int t = row & (TLEN - 1);
  float acc = load_any(cb, d, f);
#pragma unroll
  for (int k = 0; k < 4; k++) {
    int ts = t - 3 + k;
    if (ts >= 0) acc += load_any(cw, d * 4 + k, f) * sb(xraw[(size_t)(row - 3 + k) * 1024 + d]);
  }
  float s = acc / (1.f + fexp2(-acc * LOG2E));
  xh[idx] = bs(s);
}

// ---------------- scan pass 1: per-chunk transfer product P and local state S (bf16)
template <int CLEN>
__global__ __launch_bounds__(256) void scan_pass1(
    const short* __restrict__ dtf, const short* __restrict__ xh,
    const float* __restrict__ ssm, const void* __restrict__ alog,
    short* __restrict__ P, short* __restrict__ S, const unsigned int* __restrict__ x0)
{
  constexpr int NCH = TLEN / CLEN;
  __shared__ float sB[CLEN][NSTATE];
  int f = detect_f(x0);
  int tid = threadIdx.x;
  int c = blockIdx.x % NCH;
  int r = blockIdx.x / NCH;
  int dblk = r & 3, b = r >> 2;
  int d = dblk * 256 + tid;
  int t0 = c * CLEN;
  for (int i = tid; i < CLEN * NSTATE; i += 256) {
    int rr = i >> 4, cc = i & 15;
    sB[rr][cc] = ssm[(size_t)(b * TLEN + t0 + rr) * 64 + 32 + cc];
  }
  float A2[NSTATE], st[NSTATE], Pp[NSTATE];
#pragma unroll
  for (int n = 0; n < NSTATE; n++) {
    A2[n] = -fexp2(load_any(alog, d * NSTATE + n, f) * LOG2E) * LOG2E;
    st[n] = 0.f; Pp[n] = 1.f;
  }
  __syncthreads();
#pragma unroll
  for (int tt = 0; tt < CLEN; tt++) {
    size_t xi = (size_t)(b * TLEN + t0 + tt) * DI + d;
    float dtv = sb(dtf[xi]);
    float xv = sb(xh[xi]);
    float dx = dtv * xv;
#pragma unroll
    for (int n = 0; n < NSTATE; n++) {
      float e = fexp2(dtv * A2[n]);
      st[n] = e * st[n] + dx * sB[tt][n];
      Pp[n] *= e;
    }
  }
  size_t base = ((size_t)(b * NCH + c) * NSTATE) * DI + d;
#pragma unroll
  for (int n = 0; n < NSTATE; n++) {
    P[base + (size_t)n * DI] = bs(Pp[n]);
    S[base + (size_t)n * DI] = bs(st[n]);
  }
}

// ---------------- scan pass 2: combine chunk boundaries; Sin in-place into P (bf16)
__global__ __launch_bounds__(64) void scan_pass2(
    short* __restrict__ P, const short* __restrict__ S, int nchunk)
{
  int idx = blockIdx.x * 64 + threadIdx.x;  // 0..32767 = (b, n, d)
  int d = idx & (DI - 1);
  int n = (idx >> 10) & (NSTATE - 1);
  int b = idx >> 14;
  float s = 0.f;
#pragma clang loop unroll_count(4)
  for (int c = 0; c < nchunk; c++) {
    size_t o = ((size_t)(b * nchunk + c) * NSTATE + n) * DI + d;
    float p = sb(P[o]), sv = sb(S[o]);
    P[o] = bs(s);             // Sin for chunk c
    s = p * s + sv;
  }
}

// ---------------- scan pass 3: full scan + D-skip + pre-silu'd gate -> y bf16
template <int CLEN>
__global__ __launch_bounds__(256) void scan_pass3(
    const short* __restrict__ dtf, const short* __restrict__ xh,
    const float* __restrict__ ssm, const void* __restrict__ alog,
    const short* __restrict__ Sin, const short* __restrict__ gs,
    const void* __restrict__ Dvec, short* __restrict__ yh,
    const unsigned int* __restrict__ x0)
{
  constexpr int NCH = TLEN / CLEN;
  __shared__ float sBC[CLEN][2 * NSTATE];
  int f = detect_f(x0);
  int tid = threadIdx.x;
  int c = blockIdx.x % NCH;
  int r = blockIdx.x / NCH;
  int dblk = r & 3, b = r >> 2;
  int d = dblk * 256 + tid;
  int t0 = c * CLEN;
  for (int i = tid; i < CLEN * 2 * NSTATE; i += 256) {
    int rr = i >> 5, cc = i & 31;
    sBC[rr][cc] = ssm[(size_t)(b * TLEN + t0 + rr) * 64 + 32 + cc];
  }
  float A2[NSTATE], st[NSTATE];
  size_t base = ((size_t)(b * NCH + c) * NSTATE) * DI + d;
#pragma unroll
  for (int n = 0; n < NSTATE; n++) {
    A2[n] = -fexp2(load_any(alog, d * NSTATE + n, f) * LOG2E) * LOG2E;
    st[n] = sb(Sin[base + (size_t)n * DI]);
  }
  float Dd = load_any(Dvec, d, f);
  __syncthreads();
#pragma unroll
  for (int tt = 0; tt < CLEN; tt++) {
    int row = b * TLEN + t0 + tt;
    size_t xi = (size_t)row * DI + d;
    float dtv = sb(dtf[xi]);
    float xv = sb(xh[xi]);
    float dx = dtv * xv;
    float yv = 0.f;
#pragma unroll
    for (int n = 0; n < NSTATE; n++) {
      float e = fexp2(dtv * A2[n]);
      st[n] = e * st[n] + dx * sBC[tt][n];
      yv += st[n] * sBC[tt][NSTATE + n];
    }
    float out = (yv + xv * Dd) * sb(gs[xi]);
    yh[xi] = bs(out);
  }
}

extern "C" void kernel_launch(void* const* d_in, const int* in_sizes, int n_in,
                              void* d_out, int out_size, void* d_ws, size_t ws_size,
                              hipStream_t stream) {
  const void* x    = d_in[0];   // [2,2048,512]
  const void* w1   = d_in[1];   // [2048,512]
  const void* cw   = d_in[2];   // [1024,1,4]
  const void* cb   = d_in[3];   // [1024]
  const void* xw   = d_in[4];   // [64,1024]
  const void* dtw  = d_in[5];   // [1024,32]
  const void* dtb  = d_in[6];   // [1024]
  const void* alog = d_in[7];   // [1024,16]
  const void* Dv   = d_in[8];   // [1024]
  const void* w3   = d_in[9];   // [512,1024]
  const unsigned int* x0 = (const unsigned int*)x;

  char* ws = (char*)d_ws;
  short* xraw = (short*)ws;            ws += (size_t)4096 * 1024 * 2;   // 8.39 MB
  short* gs_h = (short*)ws;            ws += (size_t)4096 * 1024 * 2;   // 8.39 MB
  short* xt_h = (short*)ws;            ws += (size_t)4096 * 1024 * 2;   // 8.39 MB
  float* ssm  = (float*)ws;            ws += (size_t)4096 * 64 * 4;     // 1.05 MB
  short* y_h  = (short*)ws;            ws += (size_t)4096 * 1024 * 2;   // 8.39 MB
  short* dtf  = (short*)ws;            ws += (size_t)4096 * 1024 * 2;   // 8.39 MB
  short* smH  = (short*)ws;            ws += (size_t)622592 * 2;        // 1.25 MB
  short* sdH  = (short*)ws;            ws += (size_t)131072 * 2;        // 0.26 MB (layout keep)
  char*  R    = ws;                                                      // staging / P|S
  (void)sdH;

  size_t fixed = (size_t)(ws - (char*)d_ws);
  int nchunk = 64;    // CLEN=32: 512 blocks for pass1/3; pass2 chain 64 iters
  while (nchunk > 32) {
    size_t region = (size_t)131072 * nchunk;      // P+S bf16
    if (region < 7536640) region = 7536640;       // cast staging floor
    if (fixed + region <= ws_size) break;
    nchunk >>= 1;
  }
  int clen = TLEN / nchunk;

  short* bigH = (short*)R;                       // x @0, w1 @2097152 (hi)
  short* P    = (short*)R;                       // after in_proj: P|S (bf16)
  short* S    = (short*)(R + (size_t)65536 * nchunk);

  cast_h<<<dim3(3680), 256, 0, stream>>>(x, w1, xw, w3, dtw, bigH, smH);
  // in_proj: [4096,512] x [2048,512]^T -> xraw bf16 + silu(gate) bf16 (MODE 3)
  gemm_mf<128, 128, 3><<<dim3(32, 16), 256, 0, stream>>>(
      bigH, bigH + 2097152, nullptr, 512, 512, 512, 2048, nullptr, x0, xraw, gs_h);
  // conv + silu -> xt bf16
  conv_silu<<<dim3(16384), 256, 0, stream>>>(xraw, cw, cb, xt_h, x0);
  // fused x_proj + dt_proj: ssm fp32 (cols 32..64) + dtf bf16
  xdt_gemm<<<dim3(64, 4), 256, 0, stream>>>(
      xt_h, smH, smH + 589824, ssm, dtb, x0, dtf);
  // chunked linear-recurrence scan -> y bf16
  dim3 sg(8 * nchunk);
  switch (clen) {
    case 16:
      scan_pass1<16><<<sg, 256, 0, stream>>>(dtf, xt_h, ssm, alog, P, S, x0);
      scan_pass2<<<dim3(512), 64, 0, stream>>>(P, S, nchunk);
      scan_pass3<16><<<sg, 256, 0, stream>>>(dtf, xt_h, ssm, alog, P, gs_h, Dv, y_h, x0);
      break;
    case 32:
      scan_pass1<32><<<sg, 256, 0, stream>>>(dtf, xt_h, ssm, alog, P, S, x0);
      scan_pass2<<<dim3(512), 64, 0, stream>>>(P, S, nchunk);
      scan_pass3<32><<<sg, 256, 0, stream>>>(dtf, xt_h, ssm, alog, P, gs_h, Dv, y_h, x0);
      break;
    default:
      scan_pass1<64><<<sg, 256, 0, stream>>>(dtf, xt_h, ssm, alog, P, S, x0);
      scan_pass2<<<dim3(512), 64, 0, stream>>>(P, S, nchunk);
      scan_pass3<64><<<sg, 256, 0, stream>>>(dtf, xt_h, ssm, alog, P, gs_h, Dv, y_h, x0);
      break;
  }
  // out_proj: [4096,1024] x [512,1024]^T -> d_out fp32
  gemm_mf<64, 64, 0><<<dim3(64, 8), 256, 0, stream>>>(
      y_h, smH + 65536, (float*)d_out, 1024, 1024, 1024, 512, nullptr, x0, nullptr, nullptr);
}